// Round 1
// baseline (15703.357 us; speedup 1.0000x reference)
//
#include <hip/hip_runtime.h>
#include <math.h>

// ---- problem constants ----
constexpr int DIMC   = 768;
constexpr int NHEADS = 12;
constexpr int HD     = 64;
constexpr int NCLS   = 20;
constexpr int HID    = 3072;
constexpr int NBATCH = 16;
constexpr int NSEQ   = 596;
constexpr int NT     = NBATCH * NSEQ;   // 9536 tokens
constexpr int C3     = 3 * DIMC;        // 2304
#define LN_EPS 1e-5f

// ============================================================
// LayerNorm: one block (256 thr) per row of 768
// ============================================================
__global__ __launch_bounds__(256) void ln_kernel(const float* __restrict__ x,
                                                 const float* __restrict__ g,
                                                 const float* __restrict__ b,
                                                 float* __restrict__ y) {
    const int row = blockIdx.x;
    const float* xr = x + (size_t)row * DIMC;
    const int t = threadIdx.x;
    float v0 = xr[t];
    float v1 = xr[t + 256];
    float v2 = xr[t + 512];
    float s  = v0 + v1 + v2;
    float ss = v0 * v0 + v1 * v1 + v2 * v2;
#pragma unroll
    for (int m = 1; m < 64; m <<= 1) {
        s  += __shfl_xor(s, m);
        ss += __shfl_xor(ss, m);
    }
    __shared__ float ls[4], lss[4];
    const int wid = t >> 6;
    if ((t & 63) == 0) { ls[wid] = s; lss[wid] = ss; }
    __syncthreads();
    s  = ls[0] + ls[1] + ls[2] + ls[3];
    ss = lss[0] + lss[1] + lss[2] + lss[3];
    const float mean = s * (1.0f / DIMC);
    const float var  = ss * (1.0f / DIMC) - mean * mean;
    const float rstd = rsqrtf(var + LN_EPS);
    float* yr = y + (size_t)row * DIMC;
    int c = t;
    yr[c] = (v0 - mean) * rstd * g[c] + b[c];
    c += 256;
    yr[c] = (v1 - mean) * rstd * g[c] + b[c];
    c += 256;
    yr[c] = (v2 - mean) * rstd * g[c] + b[c];
}

// ============================================================
// GEMM: Out[M,Nn] = A[M,K] @ W[Nn,K]^T + bias (+res | gelu)
// 128x128 tile, BK=16, 256 threads, 8x8 micro-tile.
// EPI: 0 = bias, 1 = bias+residual, 2 = bias+GELU(exact)
// Requires: Nn % 128 == 0, K % 16 == 0. M guarded.
// ============================================================
__device__ __forceinline__ float gelu_f(float v) {
    return 0.5f * v * (1.0f + erff(v * 0.70710678118654752f));
}

template <int EPI>
__global__ __launch_bounds__(256) void gemm_kernel(const float* __restrict__ A,
                                                   const float* __restrict__ W,
                                                   const float* __restrict__ bias,
                                                   const float* __restrict__ res,
                                                   float* __restrict__ Out,
                                                   int M, int Nn, int K) {
    constexpr int BM = 128, BN = 128, BK = 16;
    constexpr int LDT = 132;  // padded LDS stride (words); 132*4 B = 16B-aligned rows
    __shared__ float As[BK][LDT];
    __shared__ float Ws[BK][LDT];

    const int tid = threadIdx.x;
    const int tx = tid & 15, ty = tid >> 4;
    const int m0 = blockIdx.y * BM;
    const int n0 = blockIdx.x * BN;

    float acc[8][8];
#pragma unroll
    for (int i = 0; i < 8; i++)
#pragma unroll
        for (int j = 0; j < 8; j++) acc[i][j] = 0.f;

    for (int kt = 0; kt < K; kt += BK) {
        // stage A and W tiles: 128 rows x 16 k each = 512 float4 per tile, 2/thread
#pragma unroll
        for (int l = 0; l < 2; l++) {
            const int fl  = tid + l * 256;
            const int row = fl >> 2, k4 = fl & 3;
            const int gm = m0 + row;
            float4 va = make_float4(0.f, 0.f, 0.f, 0.f);
            if (gm < M) va = *(const float4*)(A + (size_t)gm * K + kt + k4 * 4);
            As[k4 * 4 + 0][row] = va.x;
            As[k4 * 4 + 1][row] = va.y;
            As[k4 * 4 + 2][row] = va.z;
            As[k4 * 4 + 3][row] = va.w;
            const int gn = n0 + row;  // Nn % 128 == 0 -> always in bounds
            const float4 vw = *(const float4*)(W + (size_t)gn * K + kt + k4 * 4);
            Ws[k4 * 4 + 0][row] = vw.x;
            Ws[k4 * 4 + 1][row] = vw.y;
            Ws[k4 * 4 + 2][row] = vw.z;
            Ws[k4 * 4 + 3][row] = vw.w;
        }
        __syncthreads();
#pragma unroll
        for (int k = 0; k < BK; k++) {
            float a[8], w[8];
            *(float4*)&a[0] = *(const float4*)&As[k][ty * 8];
            *(float4*)&a[4] = *(const float4*)&As[k][ty * 8 + 4];
            *(float4*)&w[0] = *(const float4*)&Ws[k][tx * 8];
            *(float4*)&w[4] = *(const float4*)&Ws[k][tx * 8 + 4];
#pragma unroll
            for (int i = 0; i < 8; i++)
#pragma unroll
                for (int j = 0; j < 8; j++) acc[i][j] = fmaf(a[i], w[j], acc[i][j]);
        }
        __syncthreads();
    }

    // epilogue
#pragma unroll
    for (int i = 0; i < 8; i++) {
        const int gm = m0 + ty * 8 + i;
        if (gm < M) {
            const size_t off = (size_t)gm * Nn + n0 + tx * 8;
#pragma unroll
            for (int jv = 0; jv < 2; jv++) {
                float4 v;
                v.x = acc[i][jv * 4 + 0] + bias[n0 + tx * 8 + jv * 4 + 0];
                v.y = acc[i][jv * 4 + 1] + bias[n0 + tx * 8 + jv * 4 + 1];
                v.z = acc[i][jv * 4 + 2] + bias[n0 + tx * 8 + jv * 4 + 2];
                v.w = acc[i][jv * 4 + 3] + bias[n0 + tx * 8 + jv * 4 + 3];
                if (EPI == 1) {
                    const float4 rr = *(const float4*)(res + off + jv * 4);
                    v.x += rr.x; v.y += rr.y; v.z += rr.z; v.w += rr.w;
                } else if (EPI == 2) {
                    v.x = gelu_f(v.x); v.y = gelu_f(v.y);
                    v.z = gelu_f(v.z); v.w = gelu_f(v.w);
                }
                *(float4*)(Out + off + jv * 4) = v;
            }
        }
    }
}

// ============================================================
// Attention pass A: scores + split softmax -> weights (global)
// block = 256 thr handles 32 q-rows x all 596 keys for one (b,h).
// Per-thread: 2 q-rows x 4 keys per 64-key chunk, 10 chunks (80 scores in regs).
// ============================================================
__global__ __launch_bounds__(256) void attn_scores_kernel(const float* __restrict__ qkv,
                                                          float* __restrict__ wts) {
    constexpr int TQ = 32, CHK = 64, NCH = 10, LDK = 68;  // 68*4B: 16B-aligned rows
    __shared__ float Qs[TQ][LDK];
    __shared__ float Ks[CHK][LDK];

    const int tid = threadIdx.x;
    const int tx = tid & 15, ty = tid >> 4;
    const int q0 = blockIdx.x * TQ;
    const int bh = blockIdx.y;
    const int b = bh / NHEADS, h = bh - b * NHEADS;
    const size_t qbase = (size_t)b * NSEQ * C3 + h * HD;

    // load Q tile [32][64]
#pragma unroll
    for (int l = 0; l < 2; l++) {
        const int fl = tid + l * 256;
        const int row = fl >> 4, c4 = fl & 15;
        const int qi = q0 + row;
        float4 v = make_float4(0.f, 0.f, 0.f, 0.f);
        if (qi < NSEQ) v = *(const float4*)(qkv + qbase + (size_t)qi * C3 + c4 * 4);
        Qs[row][c4 * 4 + 0] = v.x;
        Qs[row][c4 * 4 + 1] = v.y;
        Qs[row][c4 * 4 + 2] = v.z;
        Qs[row][c4 * 4 + 3] = v.w;
    }

    float s[NCH][2][4];
#pragma unroll
    for (int ch = 0; ch < NCH; ch++)
#pragma unroll
        for (int r = 0; r < 2; r++)
#pragma unroll
            for (int j = 0; j < 4; j++) s[ch][r][j] = 0.f;

    const int qr0 = ty * 2;

#pragma unroll
    for (int ch = 0; ch < NCH; ch++) {
        __syncthreads();  // previous chunk consumed (and Q staged for ch==0)
        // load K chunk [64][64]
#pragma unroll
        for (int l = 0; l < 4; l++) {
            const int fl = tid + l * 256;
            const int row = fl >> 4, c4 = fl & 15;
            const int kk = ch * CHK + row;
            float4 v = make_float4(0.f, 0.f, 0.f, 0.f);
            if (kk < NSEQ)
                v = *(const float4*)(qkv + qbase + DIMC + (size_t)kk * C3 + c4 * 4);
            Ks[row][c4 * 4 + 0] = v.x;
            Ks[row][c4 * 4 + 1] = v.y;
            Ks[row][c4 * 4 + 2] = v.z;
            Ks[row][c4 * 4 + 3] = v.w;
        }
        __syncthreads();
#pragma unroll
        for (int d4 = 0; d4 < 16; d4++) {
            const float4 qa = *(const float4*)&Qs[qr0][d4 * 4];
            const float4 qb = *(const float4*)&Qs[qr0 + 1][d4 * 4];
#pragma unroll
            for (int j = 0; j < 4; j++) {
                const float4 kv = *(const float4*)&Ks[tx * 4 + j][d4 * 4];
                s[ch][0][j] += qa.x * kv.x + qa.y * kv.y + qa.z * kv.z + qa.w * kv.w;
                s[ch][1][j] += qb.x * kv.x + qb.y * kv.y + qb.z * kv.z + qb.w * kv.w;
            }
        }
    }

    // split softmax over key segments [0,20) and [20,596); 16 lanes (tx) hold a row
    const float scale = 0.125f;
    float inv0[2], inv1[2];
#pragma unroll
    for (int r = 0; r < 2; r++) {
        float m0 = -1e30f, m1 = -1e30f;
#pragma unroll
        for (int ch = 0; ch < NCH; ch++)
#pragma unroll
            for (int j = 0; j < 4; j++) {
                const int kj = ch * CHK + tx * 4 + j;
                const float v = s[ch][r][j] * scale;
                s[ch][r][j] = v;
                if (kj < NCLS) m0 = fmaxf(m0, v);
                else if (kj < NSEQ) m1 = fmaxf(m1, v);
            }
#pragma unroll
        for (int off = 1; off < 16; off <<= 1) {
            m0 = fmaxf(m0, __shfl_xor(m0, off));
            m1 = fmaxf(m1, __shfl_xor(m1, off));
        }
        float s0 = 0.f, s1 = 0.f;
#pragma unroll
        for (int ch = 0; ch < NCH; ch++)
#pragma unroll
            for (int j = 0; j < 4; j++) {
                const int kj = ch * CHK + tx * 4 + j;
                if (kj < NCLS) {
                    const float e = expf(s[ch][r][j] - m0);
                    s[ch][r][j] = e; s0 += e;
                } else if (kj < NSEQ) {
                    const float e = expf(s[ch][r][j] - m1);
                    s[ch][r][j] = e; s1 += e;
                }
            }
#pragma unroll
        for (int off = 1; off < 16; off <<= 1) {
            s0 += __shfl_xor(s0, off);
            s1 += __shfl_xor(s1, off);
        }
        inv0[r] = 1.f / s0;
        inv1[r] = 1.f / s1;
    }

    // write normalized weights (NCLS=20 is a multiple of 4: each float4 is one segment)
#pragma unroll
    for (int r = 0; r < 2; r++) {
        const int qi = q0 + qr0 + r;
        if (qi < NSEQ) {
            const size_t base = ((size_t)bh * NSEQ + qi) * NSEQ;
#pragma unroll
            for (int ch = 0; ch < NCH; ch++) {
                const int kj = ch * CHK + tx * 4;
                if (kj + 3 < NSEQ) {
                    const float inv = (kj < NCLS) ? inv0[r] : inv1[r];
                    float4 w;
                    w.x = s[ch][r][0] * inv;
                    w.y = s[ch][r][1] * inv;
                    w.z = s[ch][r][2] * inv;
                    w.w = s[ch][r][3] * inv;
                    *(float4*)(wts + base + kj) = w;
                }
            }
        }
    }
}

// ============================================================
// Attention pass B: O[596,64] = Wts[596,596] @ V[596,64] per (b,h)
// ============================================================
__global__ __launch_bounds__(256) void attn_av_kernel(const float* __restrict__ qkv,
                                                      const float* __restrict__ wts,
                                                      float* __restrict__ o) {
    constexpr int TQ = 32, CHK = 64, NCH = 10, LDV = 68;
    __shared__ float Wsh[TQ][LDV];
    __shared__ float Vs[CHK][LDV];

    const int tid = threadIdx.x;
    const int tx = tid & 15, ty = tid >> 4;
    const int q0 = blockIdx.x * TQ;
    const int bh = blockIdx.y;
    const int b = bh / NHEADS, h = bh - b * NHEADS;
    const size_t qbase = (size_t)b * NSEQ * C3 + h * HD;

    float acc[2][4];
#pragma unroll
    for (int r = 0; r < 2; r++)
#pragma unroll
        for (int j = 0; j < 4; j++) acc[r][j] = 0.f;

    for (int ch = 0; ch < NCH; ch++) {
        __syncthreads();
        // load weight chunk [32 q][64 k]
#pragma unroll
        for (int l = 0; l < 2; l++) {
            const int fl = tid + l * 256;
            const int row = fl >> 4, c4 = fl & 15;
            const int qi = q0 + row;
            const int kk = ch * CHK + c4 * 4;
            float4 v = make_float4(0.f, 0.f, 0.f, 0.f);
            if (qi < NSEQ && kk < NSEQ)
                v = *(const float4*)(wts + ((size_t)bh * NSEQ + qi) * NSEQ + kk);
            Wsh[row][c4 * 4 + 0] = v.x;
            Wsh[row][c4 * 4 + 1] = v.y;
            Wsh[row][c4 * 4 + 2] = v.z;
            Wsh[row][c4 * 4 + 3] = v.w;
        }
        // load V chunk [64 k][64 d]
#pragma unroll
        for (int l = 0; l < 4; l++) {
            const int fl = tid + l * 256;
            const int row = fl >> 4, c4 = fl & 15;
            const int kk = ch * CHK + row;
            float4 v = make_float4(0.f, 0.f, 0.f, 0.f);
            if (kk < NSEQ)
                v = *(const float4*)(qkv + qbase + 2 * DIMC + (size_t)kk * C3 + c4 * 4);
            Vs[row][c4 * 4 + 0] = v.x;
            Vs[row][c4 * 4 + 1] = v.y;
            Vs[row][c4 * 4 + 2] = v.z;
            Vs[row][c4 * 4 + 3] = v.w;
        }
        __syncthreads();
#pragma unroll
        for (int k4 = 0; k4 < 16; k4++) {
            const float4 wa = *(const float4*)&Wsh[ty * 2][k4 * 4];
            const float4 wb = *(const float4*)&Wsh[ty * 2 + 1][k4 * 4];
            const float4 v0 = *(const float4*)&Vs[k4 * 4 + 0][tx * 4];
            const float4 v1 = *(const float4*)&Vs[k4 * 4 + 1][tx * 4];
            const float4 v2 = *(const float4*)&Vs[k4 * 4 + 2][tx * 4];
            const float4 v3 = *(const float4*)&Vs[k4 * 4 + 3][tx * 4];
            acc[0][0] += wa.x * v0.x + wa.y * v1.x + wa.z * v2.x + wa.w * v3.x;
            acc[0][1] += wa.x * v0.y + wa.y * v1.y + wa.z * v2.y + wa.w * v3.y;
            acc[0][2] += wa.x * v0.z + wa.y * v1.z + wa.z * v2.z + wa.w * v3.z;
            acc[0][3] += wa.x * v0.w + wa.y * v1.w + wa.z * v2.w + wa.w * v3.w;
            acc[1][0] += wb.x * v0.x + wb.y * v1.x + wb.z * v2.x + wb.w * v3.x;
            acc[1][1] += wb.x * v0.y + wb.y * v1.y + wb.z * v2.y + wb.w * v3.y;
            acc[1][2] += wb.x * v0.z + wb.y * v1.z + wb.z * v2.z + wb.w * v3.z;
            acc[1][3] += wb.x * v0.w + wb.y * v1.w + wb.z * v2.w + wb.w * v3.w;
        }
    }

#pragma unroll
    for (int r = 0; r < 2; r++) {
        const int qi = q0 + ty * 2 + r;
        if (qi < NSEQ) {
            float4 v;
            v.x = acc[r][0]; v.y = acc[r][1]; v.z = acc[r][2]; v.w = acc[r][3];
            *(float4*)(o + (size_t)(b * NSEQ + qi) * DIMC + h * HD + tx * 4) = v;
        }
    }
}

// ============================================================
// launcher
// ============================================================
extern "C" void kernel_launch(void* const* d_in, const int* in_sizes, int n_in,
                              void* d_out, int out_size, void* d_ws, size_t ws_size,
                              hipStream_t stream) {
    const float* x      = (const float*)d_in[0];
    const float* qkv_w  = (const float*)d_in[1];
    const float* qkv_b  = (const float*)d_in[2];
    const float* proj_w = (const float*)d_in[3];
    const float* proj_b = (const float*)d_in[4];
    const float* ln1_g  = (const float*)d_in[5];
    const float* ln1_b  = (const float*)d_in[6];
    const float* ln2_g  = (const float*)d_in[7];
    const float* ln2_b  = (const float*)d_in[8];
    const float* fc1_w  = (const float*)d_in[9];
    const float* fc1_b  = (const float*)d_in[10];
    const float* fc2_w  = (const float*)d_in[11];
    const float* fc2_b  = (const float*)d_in[12];

    float* out0 = (float*)d_out;                       // [16,596,768]
    float* wts  = out0 + (size_t)NT * DIMC;            // [16,12,596,596]

    // workspace layout (floats):
    //   bufA: max(qkv 9536x2304, hidden 9536x3072) = 29,294,592
    //   bufB: 9536x768  (xln -> attn_out -> ln2_out)
    //   bufC: 9536x768  (x1 = x + proj)
    float* bufA = (float*)d_ws;
    float* bufB = bufA + (size_t)NT * HID;
    float* bufC = bufB + (size_t)NT * DIMC;

    float* qkv  = bufA;
    float* xln  = bufB;
    float* obuf = bufB;
    float* x1   = bufC;
    float* hbuf = bufB;
    float* hh   = bufA;

    // 1. LN1
    ln_kernel<<<NT, 256, 0, stream>>>(x, ln1_g, ln1_b, xln);
    // 2. QKV GEMM  [9536,2304]
    gemm_kernel<0><<<dim3(C3 / 128, (NT + 127) / 128), 256, 0, stream>>>(
        xln, qkv_w, qkv_b, nullptr, qkv, NT, C3, DIMC);
    // 3. scores + split softmax -> weights output
    attn_scores_kernel<<<dim3((NSEQ + 31) / 32, NBATCH * NHEADS), 256, 0, stream>>>(qkv, wts);
    // 4. attn @ V -> obuf [9536,768]
    attn_av_kernel<<<dim3((NSEQ + 31) / 32, NBATCH * NHEADS), 256, 0, stream>>>(qkv, wts, obuf);
    // 5. proj GEMM + residual(x) -> x1
    gemm_kernel<1><<<dim3(DIMC / 128, (NT + 127) / 128), 256, 0, stream>>>(
        obuf, proj_w, proj_b, x, x1, NT, DIMC, DIMC);
    // 6. LN2
    ln_kernel<<<NT, 256, 0, stream>>>(x1, ln2_g, ln2_b, hbuf);
    // 7. FC1 GEMM + GELU -> hh [9536,3072]
    gemm_kernel<2><<<dim3(HID / 128, (NT + 127) / 128), 256, 0, stream>>>(
        hbuf, fc1_w, fc1_b, nullptr, hh, NT, HID, DIMC);
    // 8. FC2 GEMM + residual(x1) -> out0
    gemm_kernel<1><<<dim3(DIMC / 128, (NT + 127) / 128), 256, 0, stream>>>(
        hh, fc2_w, fc2_b, x1, out0, NT, DIMC, HID);
}

// Round 2
// 2986.626 us; speedup vs baseline: 5.2579x; 5.2579x over previous
//
#include <hip/hip_runtime.h>
#include <math.h>

// ---- problem constants ----
constexpr int DIMC   = 768;
constexpr int NHEADS = 12;
constexpr int HD     = 64;
constexpr int NCLS   = 20;
constexpr int HID    = 3072;
constexpr int NBATCH = 16;
constexpr int NSEQ   = 596;
constexpr int NT     = NBATCH * NSEQ;   // 9536 tokens
constexpr int C3     = 3 * DIMC;        // 2304
#define LN_EPS 1e-5f

// ============================================================
// LayerNorm: one block (256 thr) per row of 768
// ============================================================
__global__ __launch_bounds__(256) void ln_kernel(const float* __restrict__ x,
                                                 const float* __restrict__ g,
                                                 const float* __restrict__ b,
                                                 float* __restrict__ y) {
    const int row = blockIdx.x;
    const float* xr = x + (size_t)row * DIMC;
    const int t = threadIdx.x;
    float v0 = xr[t];
    float v1 = xr[t + 256];
    float v2 = xr[t + 512];
    float s  = v0 + v1 + v2;
    float ss = v0 * v0 + v1 * v1 + v2 * v2;
#pragma unroll
    for (int m = 1; m < 64; m <<= 1) {
        s  += __shfl_xor(s, m);
        ss += __shfl_xor(ss, m);
    }
    __shared__ float ls[4], lss[4];
    const int wid = t >> 6;
    if ((t & 63) == 0) { ls[wid] = s; lss[wid] = ss; }
    __syncthreads();
    s  = ls[0] + ls[1] + ls[2] + ls[3];
    ss = lss[0] + lss[1] + lss[2] + lss[3];
    const float mean = s * (1.0f / DIMC);
    const float var  = ss * (1.0f / DIMC) - mean * mean;
    const float rstd = rsqrtf(var + LN_EPS);
    float* yr = y + (size_t)row * DIMC;
    int c = t;
    yr[c] = (v0 - mean) * rstd * g[c] + b[c];
    c += 256;
    yr[c] = (v1 - mean) * rstd * g[c] + b[c];
    c += 256;
    yr[c] = (v2 - mean) * rstd * g[c] + b[c];
}

// ============================================================
// GEMM: Out[M,Nn] = A[M,K] @ W[Nn,K]^T + bias (+res | gelu)
// 128x128 tile, BK=16, 256 threads, 8x8 micro-tile.
// EPI: 0 = bias, 1 = bias+residual, 2 = bias+GELU(exact)
// Requires: Nn % 128 == 0, K % 16 == 0. M guarded.
// ============================================================
__device__ __forceinline__ float gelu_f(float v) {
    return 0.5f * v * (1.0f + erff(v * 0.70710678118654752f));
}

template <int EPI>
__global__ __launch_bounds__(256) void gemm_kernel(const float* __restrict__ A,
                                                   const float* __restrict__ W,
                                                   const float* __restrict__ bias,
                                                   const float* __restrict__ res,
                                                   float* __restrict__ Out,
                                                   int M, int Nn, int K) {
    constexpr int BM = 128, BN = 128, BK = 16;
    constexpr int LDT = 132;  // padded LDS stride (words); 132*4 B = 16B-aligned rows
    __shared__ float As[BK][LDT];
    __shared__ float Ws[BK][LDT];

    const int tid = threadIdx.x;
    const int tx = tid & 15, ty = tid >> 4;
    const int m0 = blockIdx.y * BM;
    const int n0 = blockIdx.x * BN;

    float acc[8][8];
#pragma unroll
    for (int i = 0; i < 8; i++)
#pragma unroll
        for (int j = 0; j < 8; j++) acc[i][j] = 0.f;

    for (int kt = 0; kt < K; kt += BK) {
        // stage A and W tiles: 128 rows x 16 k each = 512 float4 per tile, 2/thread
#pragma unroll
        for (int l = 0; l < 2; l++) {
            const int fl  = tid + l * 256;
            const int row = fl >> 2, k4 = fl & 3;
            const int gm = m0 + row;
            float4 va = make_float4(0.f, 0.f, 0.f, 0.f);
            if (gm < M) va = *(const float4*)(A + (size_t)gm * K + kt + k4 * 4);
            As[k4 * 4 + 0][row] = va.x;
            As[k4 * 4 + 1][row] = va.y;
            As[k4 * 4 + 2][row] = va.z;
            As[k4 * 4 + 3][row] = va.w;
            const int gn = n0 + row;  // Nn % 128 == 0 -> always in bounds
            const float4 vw = *(const float4*)(W + (size_t)gn * K + kt + k4 * 4);
            Ws[k4 * 4 + 0][row] = vw.x;
            Ws[k4 * 4 + 1][row] = vw.y;
            Ws[k4 * 4 + 2][row] = vw.z;
            Ws[k4 * 4 + 3][row] = vw.w;
        }
        __syncthreads();
#pragma unroll
        for (int k = 0; k < BK; k++) {
            float a[8], w[8];
            *(float4*)&a[0] = *(const float4*)&As[k][ty * 8];
            *(float4*)&a[4] = *(const float4*)&As[k][ty * 8 + 4];
            *(float4*)&w[0] = *(const float4*)&Ws[k][tx * 8];
            *(float4*)&w[4] = *(const float4*)&Ws[k][tx * 8 + 4];
#pragma unroll
            for (int i = 0; i < 8; i++)
#pragma unroll
                for (int j = 0; j < 8; j++) acc[i][j] = fmaf(a[i], w[j], acc[i][j]);
        }
        __syncthreads();
    }

    // epilogue
#pragma unroll
    for (int i = 0; i < 8; i++) {
        const int gm = m0 + ty * 8 + i;
        if (gm < M) {
            const size_t off = (size_t)gm * Nn + n0 + tx * 8;
#pragma unroll
            for (int jv = 0; jv < 2; jv++) {
                float4 v;
                v.x = acc[i][jv * 4 + 0] + bias[n0 + tx * 8 + jv * 4 + 0];
                v.y = acc[i][jv * 4 + 1] + bias[n0 + tx * 8 + jv * 4 + 1];
                v.z = acc[i][jv * 4 + 2] + bias[n0 + tx * 8 + jv * 4 + 2];
                v.w = acc[i][jv * 4 + 3] + bias[n0 + tx * 8 + jv * 4 + 3];
                if (EPI == 1) {
                    const float4 rr = *(const float4*)(res + off + jv * 4);
                    v.x += rr.x; v.y += rr.y; v.z += rr.z; v.w += rr.w;
                } else if (EPI == 2) {
                    v.x = gelu_f(v.x); v.y = gelu_f(v.y);
                    v.z = gelu_f(v.z); v.w = gelu_f(v.w);
                }
                *(float4*)(Out + off + jv * 4) = v;
            }
        }
    }
}

// ============================================================
// Attention pass A (v2): scores -> LDS -> split softmax -> weights
// One block = 16 q-rows x all 596 keys for one (b,h).
// Scores live in LDS (S[16][644] = 41 KB), NOT registers -> no spills.
// Thread (ty,tx): row ty, 4 key-cols (tx*4..) per 64-key chunk.
// The 16 threads owning a row are contiguous lanes within one wave,
// so __shfl_xor width-16 reductions work for the row softmax.
// ============================================================
__global__ __launch_bounds__(256) void attn_scores_kernel(const float* __restrict__ qkv,
                                                          float* __restrict__ wts) {
    constexpr int TQ = 16, CHK = 64, NCH = 10, LDK = 68;
    constexpr int LDS_S = 644;  // >= 640 cols, %32 == 4 to stagger banks per row
    __shared__ float S[TQ][LDS_S];    // 41,216 B
    __shared__ float Qs[TQ][LDK];     //  4,352 B
    __shared__ float Ks[CHK][LDK];    // 17,408 B   total 62,976 B

    const int tid = threadIdx.x;
    const int tx = tid & 15, ty = tid >> 4;
    const int q0 = blockIdx.x * TQ;
    const int bh = blockIdx.y;
    const int b = bh / NHEADS, h = bh - b * NHEADS;
    const size_t qbase = (size_t)b * NSEQ * C3 + h * HD;

    // load Q tile [16][64]: exactly one float4 per thread
    {
        const int qi = q0 + ty;
        float4 v = make_float4(0.f, 0.f, 0.f, 0.f);
        if (qi < NSEQ) v = *(const float4*)(qkv + qbase + (size_t)qi * C3 + tx * 4);
        Qs[ty][tx * 4 + 0] = v.x;
        Qs[ty][tx * 4 + 1] = v.y;
        Qs[ty][tx * 4 + 2] = v.z;
        Qs[ty][tx * 4 + 3] = v.w;
    }

    const float scale = 0.125f;

    for (int ch = 0; ch < NCH; ch++) {
        __syncthreads();  // previous K chunk consumed (and Qs visible for ch==0)
        // load K chunk [64][64]: 4 float4 per thread
#pragma unroll
        for (int l = 0; l < 4; l++) {
            const int fl = tid + l * 256;
            const int row = fl >> 4, c4 = fl & 15;
            const int kk = ch * CHK + row;
            float4 v = make_float4(0.f, 0.f, 0.f, 0.f);
            if (kk < NSEQ)
                v = *(const float4*)(qkv + qbase + DIMC + (size_t)kk * C3 + c4 * 4);
            Ks[row][c4 * 4 + 0] = v.x;
            Ks[row][c4 * 4 + 1] = v.y;
            Ks[row][c4 * 4 + 2] = v.z;
            Ks[row][c4 * 4 + 3] = v.w;
        }
        __syncthreads();

        float acc[4] = {0.f, 0.f, 0.f, 0.f};
#pragma unroll
        for (int d4 = 0; d4 < 16; d4++) {
            const float4 q = *(const float4*)&Qs[ty][d4 * 4];
#pragma unroll
            for (int j = 0; j < 4; j++) {
                const float4 kv = *(const float4*)&Ks[tx * 4 + j][d4 * 4];
                acc[j] += q.x * kv.x + q.y * kv.y + q.z * kv.z + q.w * kv.w;
            }
        }
        float4 sv;
        sv.x = acc[0] * scale; sv.y = acc[1] * scale;
        sv.z = acc[2] * scale; sv.w = acc[3] * scale;
        *(float4*)&S[ty][ch * CHK + tx * 4] = sv;
    }
    __syncthreads();

    // ---- split softmax over row ty; 16 lanes per row (contiguous in a wave) ----
    // float4-column chunks: c4 in [0,149); c4 < 5 -> CLS segment (cols 0..19)
    float m0 = -1e30f, m1 = -1e30f;
#pragma unroll
    for (int i = 0; i < 10; i++) {
        const int c4 = tx + 16 * i;
        if (c4 < 149) {
            const float4 v = *(const float4*)&S[ty][c4 * 4];
            const float mv = fmaxf(fmaxf(v.x, v.y), fmaxf(v.z, v.w));
            if (c4 < 5) m0 = fmaxf(m0, mv);
            else        m1 = fmaxf(m1, mv);
        }
    }
#pragma unroll
    for (int off = 1; off < 16; off <<= 1) {
        m0 = fmaxf(m0, __shfl_xor(m0, off));
        m1 = fmaxf(m1, __shfl_xor(m1, off));
    }
    float s0 = 0.f, s1 = 0.f;
#pragma unroll
    for (int i = 0; i < 10; i++) {
        const int c4 = tx + 16 * i;
        if (c4 < 149) {
            const float m = (c4 < 5) ? m0 : m1;
            float4 v = *(const float4*)&S[ty][c4 * 4];
            v.x = expf(v.x - m); v.y = expf(v.y - m);
            v.z = expf(v.z - m); v.w = expf(v.w - m);
            *(float4*)&S[ty][c4 * 4] = v;
            const float sum = v.x + v.y + v.z + v.w;
            if (c4 < 5) s0 += sum;
            else        s1 += sum;
        }
    }
#pragma unroll
    for (int off = 1; off < 16; off <<= 1) {
        s0 += __shfl_xor(s0, off);
        s1 += __shfl_xor(s1, off);
    }
    const float inv0 = 1.f / s0, inv1 = 1.f / s1;

    const int qi = q0 + ty;
    if (qi < NSEQ) {
        const size_t base = ((size_t)bh * NSEQ + qi) * NSEQ;
#pragma unroll
        for (int i = 0; i < 10; i++) {
            const int c4 = tx + 16 * i;
            if (c4 < 149) {
                const float inv = (c4 < 5) ? inv0 : inv1;
                float4 v = *(const float4*)&S[ty][c4 * 4];
                v.x *= inv; v.y *= inv; v.z *= inv; v.w *= inv;
                *(float4*)(wts + base + c4 * 4) = v;
            }
        }
    }
}

// ============================================================
// Attention pass B: O[596,64] = Wts[596,596] @ V[596,64] per (b,h)
// ============================================================
__global__ __launch_bounds__(256) void attn_av_kernel(const float* __restrict__ qkv,
                                                      const float* __restrict__ wts,
                                                      float* __restrict__ o) {
    constexpr int TQ = 32, CHK = 64, NCH = 10, LDV = 68;
    __shared__ float Wsh[TQ][LDV];
    __shared__ float Vs[CHK][LDV];

    const int tid = threadIdx.x;
    const int tx = tid & 15, ty = tid >> 4;
    const int q0 = blockIdx.x * TQ;
    const int bh = blockIdx.y;
    const int b = bh / NHEADS, h = bh - b * NHEADS;
    const size_t qbase = (size_t)b * NSEQ * C3 + h * HD;

    float acc[2][4];
#pragma unroll
    for (int r = 0; r < 2; r++)
#pragma unroll
        for (int j = 0; j < 4; j++) acc[r][j] = 0.f;

    for (int ch = 0; ch < NCH; ch++) {
        __syncthreads();
        // load weight chunk [32 q][64 k]
#pragma unroll
        for (int l = 0; l < 2; l++) {
            const int fl = tid + l * 256;
            const int row = fl >> 4, c4 = fl & 15;
            const int qi = q0 + row;
            const int kk = ch * CHK + c4 * 4;
            float4 v = make_float4(0.f, 0.f, 0.f, 0.f);
            if (qi < NSEQ && kk < NSEQ)
                v = *(const float4*)(wts + ((size_t)bh * NSEQ + qi) * NSEQ + kk);
            Wsh[row][c4 * 4 + 0] = v.x;
            Wsh[row][c4 * 4 + 1] = v.y;
            Wsh[row][c4 * 4 + 2] = v.z;
            Wsh[row][c4 * 4 + 3] = v.w;
        }
        // load V chunk [64 k][64 d]
#pragma unroll
        for (int l = 0; l < 4; l++) {
            const int fl = tid + l * 256;
            const int row = fl >> 4, c4 = fl & 15;
            const int kk = ch * CHK + row;
            float4 v = make_float4(0.f, 0.f, 0.f, 0.f);
            if (kk < NSEQ)
                v = *(const float4*)(qkv + qbase + 2 * DIMC + (size_t)kk * C3 + c4 * 4);
            Vs[row][c4 * 4 + 0] = v.x;
            Vs[row][c4 * 4 + 1] = v.y;
            Vs[row][c4 * 4 + 2] = v.z;
            Vs[row][c4 * 4 + 3] = v.w;
        }
        __syncthreads();
#pragma unroll
        for (int k4 = 0; k4 < 16; k4++) {
            const float4 wa = *(const float4*)&Wsh[ty * 2][k4 * 4];
            const float4 wb = *(const float4*)&Wsh[ty * 2 + 1][k4 * 4];
            const float4 v0 = *(const float4*)&Vs[k4 * 4 + 0][tx * 4];
            const float4 v1 = *(const float4*)&Vs[k4 * 4 + 1][tx * 4];
            const float4 v2 = *(const float4*)&Vs[k4 * 4 + 2][tx * 4];
            const float4 v3 = *(const float4*)&Vs[k4 * 4 + 3][tx * 4];
            acc[0][0] += wa.x * v0.x + wa.y * v1.x + wa.z * v2.x + wa.w * v3.x;
            acc[0][1] += wa.x * v0.y + wa.y * v1.y + wa.z * v2.y + wa.w * v3.y;
            acc[0][2] += wa.x * v0.z + wa.y * v1.z + wa.z * v2.z + wa.w * v3.z;
            acc[0][3] += wa.x * v0.w + wa.y * v1.w + wa.z * v2.w + wa.w * v3.w;
            acc[1][0] += wb.x * v0.x + wb.y * v1.x + wb.z * v2.x + wb.w * v3.x;
            acc[1][1] += wb.x * v0.y + wb.y * v1.y + wb.z * v2.y + wb.w * v3.y;
            acc[1][2] += wb.x * v0.z + wb.y * v1.z + wb.z * v2.z + wb.w * v3.z;
            acc[1][3] += wb.x * v0.w + wb.y * v1.w + wb.z * v2.w + wb.w * v3.w;
        }
    }

#pragma unroll
    for (int r = 0; r < 2; r++) {
        const int qi = q0 + ty * 2 + r;
        if (qi < NSEQ) {
            float4 v;
            v.x = acc[r][0]; v.y = acc[r][1]; v.z = acc[r][2]; v.w = acc[r][3];
            *(float4*)(o + (size_t)(b * NSEQ + qi) * DIMC + h * HD + tx * 4) = v;
        }
    }
}

// ============================================================
// launcher
// ============================================================
extern "C" void kernel_launch(void* const* d_in, const int* in_sizes, int n_in,
                              void* d_out, int out_size, void* d_ws, size_t ws_size,
                              hipStream_t stream) {
    const float* x      = (const float*)d_in[0];
    const float* qkv_w  = (const float*)d_in[1];
    const float* qkv_b  = (const float*)d_in[2];
    const float* proj_w = (const float*)d_in[3];
    const float* proj_b = (const float*)d_in[4];
    const float* ln1_g  = (const float*)d_in[5];
    const float* ln1_b  = (const float*)d_in[6];
    const float* ln2_g  = (const float*)d_in[7];
    const float* ln2_b  = (const float*)d_in[8];
    const float* fc1_w  = (const float*)d_in[9];
    const float* fc1_b  = (const float*)d_in[10];
    const float* fc2_w  = (const float*)d_in[11];
    const float* fc2_b  = (const float*)d_in[12];

    float* out0 = (float*)d_out;                       // [16,596,768]
    float* wts  = out0 + (size_t)NT * DIMC;            // [16,12,596,596]

    // workspace layout (floats):
    //   bufA: max(qkv 9536x2304, hidden 9536x3072) = 29,294,592
    //   bufB: 9536x768  (xln -> attn_out -> ln2_out)
    //   bufC: 9536x768  (x1 = x + proj)
    float* bufA = (float*)d_ws;
    float* bufB = bufA + (size_t)NT * HID;
    float* bufC = bufB + (size_t)NT * DIMC;

    float* qkv  = bufA;
    float* xln  = bufB;
    float* obuf = bufB;
    float* x1   = bufC;
    float* hbuf = bufB;
    float* hh   = bufA;

    // 1. LN1
    ln_kernel<<<NT, 256, 0, stream>>>(x, ln1_g, ln1_b, xln);
    // 2. QKV GEMM  [9536,2304]
    gemm_kernel<0><<<dim3(C3 / 128, (NT + 127) / 128), 256, 0, stream>>>(
        xln, qkv_w, qkv_b, nullptr, qkv, NT, C3, DIMC);
    // 3. scores + split softmax -> weights output (16 q-rows per block)
    attn_scores_kernel<<<dim3((NSEQ + 15) / 16, NBATCH * NHEADS), 256, 0, stream>>>(qkv, wts);
    // 4. attn @ V -> obuf [9536,768]
    attn_av_kernel<<<dim3((NSEQ + 31) / 32, NBATCH * NHEADS), 256, 0, stream>>>(qkv, wts, obuf);
    // 5. proj GEMM + residual(x) -> x1
    gemm_kernel<1><<<dim3(DIMC / 128, (NT + 127) / 128), 256, 0, stream>>>(
        obuf, proj_w, proj_b, x, x1, NT, DIMC, DIMC);
    // 6. LN2
    ln_kernel<<<NT, 256, 0, stream>>>(x1, ln2_g, ln2_b, hbuf);
    // 7. FC1 GEMM + GELU -> hh [9536,3072]
    gemm_kernel<2><<<dim3(HID / 128, (NT + 127) / 128), 256, 0, stream>>>(
        hbuf, fc1_w, fc1_b, nullptr, hh, NT, HID, DIMC);
    // 8. FC2 GEMM + residual(x1) -> out0
    gemm_kernel<1><<<dim3(DIMC / 128, (NT + 127) / 128), 256, 0, stream>>>(
        hh, fc2_w, fc2_b, x1, out0, NT, DIMC, HID);
}